// Round 12
// baseline (12557.979 us; speedup 1.0000x reference)
//
#include <hip/hip_runtime.h>
#include <math.h>

#define EPS_BN 1e-5f
#define NEG_INF (-1e30f)

constexpr int NPTS = 2048;
constexpr int KNB = 20;
constexpr int TQ = 8;   // queries per kNN block

// ---------------------------------------------------------------------------
// Tiled kNN (validated R7): one block per (b, 8 queries). Distance-phase float
// accumulation order EXACTLY preserved (self-distance exactly 0; top-k order
// isomorphic to lax.top_k). DO NOT change this code path.
// ---------------------------------------------------------------------------
template<int C>
__global__ __launch_bounds__(256) void knn_kernel(const float* __restrict__ X,
                                                  int ld, int coff,
                                                  int* __restrict__ idx) {
  constexpr int CP = (C < 4) ? 4 : C;
  const int qt = blockIdx.x, b = blockIdx.y;
  const int q0 = qt * TQ;
  const int tid = threadIdx.x;
  const float* Xb = X + (size_t)b * NPTS * ld + coff;

  __shared__ float xq[TQ][CP];
  __shared__ float d2q[TQ];
  __shared__ float pd[TQ][NPTS];
  __shared__ unsigned long long cands[TQ][4 * KNB];

  for (int t = tid; t < TQ * C; t += 256) {
    int q = t / C, c = t - q * C;
    xq[q][c] = Xb[(size_t)(q0 + q) * ld + c];
  }
  __syncthreads();

  if (tid < TQ) {
    float d2n = 0.f;
    if constexpr (C % 4 == 0) {
      const float4* u4 = (const float4*)xq[tid];
      for (int c4 = 0; c4 < C / 4; ++c4) {
        float4 u = u4[c4];
        d2n += u.x * u.x; d2n += u.y * u.y; d2n += u.z * u.z; d2n += u.w * u.w;
      }
    } else {
      #pragma unroll
      for (int c = 0; c < C; ++c) d2n += xq[tid][c] * xq[tid][c];
    }
    d2q[tid] = d2n;
  }
  __syncthreads();

  for (int m = tid; m < NPTS; m += 256) {
    const float* xm = Xb + (size_t)m * ld;
    float dot[TQ];
    #pragma unroll
    for (int q = 0; q < TQ; ++q) dot[q] = 0.f;
    float d2m = 0.f;
    if constexpr (C % 4 == 0) {
      const float4* xm4 = (const float4*)xm;
      for (int c4 = 0; c4 < C / 4; ++c4) {
        float4 v = xm4[c4];
        d2m += v.x * v.x; d2m += v.y * v.y; d2m += v.z * v.z; d2m += v.w * v.w;
        #pragma unroll
        for (int q = 0; q < TQ; ++q) {
          float4 u = ((const float4*)xq[q])[c4];
          dot[q] += u.x * v.x; dot[q] += u.y * v.y;
          dot[q] += u.z * v.z; dot[q] += u.w * v.w;
        }
      }
    } else {
      float r[CP];
      #pragma unroll
      for (int c = 0; c < C; ++c) { r[c] = xm[c]; d2m += r[c] * r[c]; }
      #pragma unroll
      for (int q = 0; q < TQ; ++q) {
        #pragma unroll
        for (int c = 0; c < C; ++c) dot[q] += xq[q][c] * r[c];
      }
    }
    #pragma unroll
    for (int q = 0; q < TQ; ++q) pd[q][m] = 2.f * dot[q] - d2q[q] - d2m;
  }
  __syncthreads();

  const int w = tid >> 6, lane = tid & 63;
  for (int q = 0; q < TQ; ++q) {
    unsigned long long key[8];
    #pragma unroll
    for (int r = 0; r < 8; ++r) {
      const int m = (w << 9) + (r << 6) + lane;
      unsigned int u = __float_as_uint(pd[q][m]);
      u = (u & 0x80000000u) ? ~u : (u | 0x80000000u);  // monotone float->uint
      key[r] = ((unsigned long long)u << 32) |
               (unsigned long long)(0xFFFFFFFFu - (unsigned int)m);
    }
    unsigned long long prev = ~0ull;
    for (int k = 0; k < KNB; ++k) {
      unsigned long long best = 0ull;
      #pragma unroll
      for (int r = 0; r < 8; ++r) {
        unsigned long long c = key[r];
        if (c < prev && c > best) best = c;
      }
      #pragma unroll
      for (int off = 32; off > 0; off >>= 1) {
        unsigned long long o = __shfl_xor(best, off, 64);
        if (o > best) best = o;
      }
      if (lane == 0) cands[q][w * KNB + k] = best;
      prev = best;
    }
  }
  __syncthreads();

  for (int q = w; q < TQ; q += 4) {
    unsigned long long a = cands[q][lane];
    unsigned long long bq = (lane < 16) ? cands[q][64 + lane] : 0ull;
    int* out = idx + ((size_t)b * NPTS + q0 + q) * KNB;
    unsigned long long pv = ~0ull;
    for (int k = 0; k < KNB; ++k) {
      unsigned long long best = 0ull;
      if (a < pv && a > best) best = a;
      if (bq < pv && bq > best) best = bq;
      #pragma unroll
      for (int off = 32; off > 0; off >>= 1) {
        unsigned long long o = __shfl_xor(best, off, 64);
        if (o > best) best = o;
      }
      if (lane == 0)
        out[k] = (int)(0xFFFFFFFFu - (unsigned int)(best & 0xFFFFFFFFull));
      pv = best;
    }
  }
}

// ---------------------------------------------------------------------------
// edgeconv_pt: one (b, n) point per block; 256 thr = 4 row-groups x 64 lanes.
// nbr rows in LDS are read via wave-uniform address -> FREE broadcast; lanes
// span output channels (o = j*64 + ow). Thread computes acc[5 rows][JO outs]:
// per c4-iter 5 ds_read + JO W-loads + 20*JO fmac -> VALU-bound (vs R11's
// latency-bound 41% VALUBusy). max_k(ct + h_k) = ct + max_k h_k.
// ---------------------------------------------------------------------------
template<int C, int O, int JO>
__global__ __launch_bounds__(256) void edgeconv_pt(
    const float* __restrict__ X, int ldx, int coff,
    const int* __restrict__ idx,
    const float* __restrict__ W,   // [O][2C]
    const float* __restrict__ bnp, // [4][O]
    float* __restrict__ Y, int ldy, int yoff) {
  static_assert(C % 4 == 0, "C multiple of 4");
  static_assert(O == JO * 64, "O = JO*64");
  constexpr int RPG = 5;  // rows per group: 4 groups x 5 = 20 neighbors
  const int n = blockIdx.x, b = blockIdx.y;
  const int tid = threadIdx.x;
  const int rg = tid >> 6, ow = tid & 63;
  const float* Xb = X + (size_t)b * NPTS * ldx + coff;

  __shared__ int ids[KNB];
  __shared__ float ctr[C];
  __shared__ float nbr[KNB][C];
  __shared__ float redm[4][JO][64];

  if (tid < KNB) ids[tid] = idx[((size_t)b * NPTS + n) * KNB + tid];
  for (int c = tid; c < C; c += 256) ctr[c] = Xb[(size_t)n * ldx + c];
  __syncthreads();
  for (int t = tid; t < KNB * (C / 4); t += 256) {
    int k = t / (C / 4), c4 = t - k * (C / 4);
    ((float4*)nbr[k])[c4] = ((const float4*)(Xb + (size_t)ids[k] * ldx))[c4];
  }
  __syncthreads();

  // center terms: ct[j] = dot(W2[o]-W1[o], ctr) for o = j*64+ow
  float ct[JO];
  #pragma unroll
  for (int j = 0; j < JO; ++j) {
    const float* Wo = W + (size_t)(j * 64 + ow) * 2 * C;
    float c0 = 0.f;
    for (int c4 = 0; c4 < C / 4; ++c4) {
      float4 a = ((const float4*)Wo)[c4];
      float4 bb = ((const float4*)(Wo + C))[c4];
      float4 u = ((const float4*)ctr)[c4];
      c0 += (bb.x - a.x) * u.x + (bb.y - a.y) * u.y +
            (bb.z - a.z) * u.z + (bb.w - a.w) * u.w;
    }
    ct[j] = c0;
  }

  // main: acc[i][j] = dot(W1[o_j], nbr[rg*5+i])
  float acc[RPG][JO];
  #pragma unroll
  for (int i = 0; i < RPG; ++i)
    #pragma unroll
    for (int j = 0; j < JO; ++j) acc[i][j] = 0.f;

  for (int c4 = 0; c4 < C / 4; ++c4) {
    float4 wv[JO];
    #pragma unroll
    for (int j = 0; j < JO; ++j)
      wv[j] = ((const float4*)(W + (size_t)(j * 64 + ow) * 2 * C))[c4];
    float4 r[RPG];
    #pragma unroll
    for (int i = 0; i < RPG; ++i)
      r[i] = ((const float4*)nbr[rg * RPG + i])[c4];  // wave-uniform: broadcast
    #pragma unroll
    for (int i = 0; i < RPG; ++i)
      #pragma unroll
      for (int j = 0; j < JO; ++j)
        acc[i][j] += wv[j].x * r[i].x + wv[j].y * r[i].y +
                     wv[j].z * r[i].z + wv[j].w * r[i].w;
  }

  #pragma unroll
  for (int j = 0; j < JO; ++j) {
    float m = acc[0][j];
    #pragma unroll
    for (int i = 1; i < RPG; ++i) m = fmaxf(m, acc[i][j]);
    redm[rg][j][ow] = m;
  }
  __syncthreads();

  if (rg == 0) {
    #pragma unroll
    for (int j = 0; j < JO; ++j) {
      float m = redm[0][j][ow];
      m = fmaxf(m, redm[1][j][ow]);
      m = fmaxf(m, redm[2][j][ow]);
      m = fmaxf(m, redm[3][j][ow]);
      const int o = j * 64 + ow;
      float hmax = ct[j] + m;
      float gg = bnp[o], be = bnp[O + o], mm = bnp[2 * O + o], vv = bnp[3 * O + o];
      float s = gg / sqrtf(vv + EPS_BN);
      float y = (hmax - mm) * s + be;
      Y[((size_t)b * NPTS + n) * ldy + yoff + o] = (y > 0.f) ? y : 0.2f * y;
    }
  }
}

// ---------------------------------------------------------------------------
// Old tiled EdgeConv (validated R8/R11 body) -- kept for the C==3 layer only.
// ---------------------------------------------------------------------------
template<int C, int O, int PT, int PO>
__global__ __launch_bounds__(PT * (O / PO)) void edgeconv_tiled(
    const float* __restrict__ X, int ldx, int coff,
    const int* __restrict__ idx,
    const float* __restrict__ W,   // [O][2C]
    const float* __restrict__ bnp, // [4][O]
    float* __restrict__ Y, int ldy, int yoff) {
  constexpr int TPP = O / PO;
  constexpr int NT = PT * TPP;
  constexpr int CP = (C < 4) ? 4 : C;
  const int n0 = blockIdx.x * PT, b = blockIdx.y;
  const int tid = threadIdx.x;
  const float* Xb = X + (size_t)b * NPTS * ldx + coff;

  __shared__ float ctr[PT][CP];
  __shared__ float nbr[PT][KNB][CP];
  __shared__ int ids[PT][KNB];

  for (int t = tid; t < PT * KNB; t += NT) {
    int p = t / KNB, k = t - p * KNB;
    ids[p][k] = idx[((size_t)b * NPTS + n0 + p) * KNB + k];
  }
  for (int t = tid; t < PT * C; t += NT) {
    int p = t / C, c = t - p * C;
    ctr[p][c] = Xb[(size_t)(n0 + p) * ldx + c];
  }
  __syncthreads();
  for (int t = tid; t < PT * KNB * C; t += NT) {
    int p = t / (KNB * C), r = t - p * (KNB * C);
    int k = r / C, c = r - k * C;
    nbr[p][k][c] = Xb[(size_t)ids[p][k] * ldx + c];
  }
  __syncthreads();

  const int pp = tid / TPP;
  const int tpp = tid - pp * TPP;

  float h[PO][KNB];

  if constexpr (C % 4 == 0) {
    #pragma unroll
    for (int po = 0; po < PO; ++po) {
      const int o = po * TPP + tpp;
      const float* Wo = W + (size_t)o * 2 * C;
      float ct = 0.f;
      for (int c4 = 0; c4 < C / 4; ++c4) {
        float4 a = ((const float4*)Wo)[c4];
        float4 bb = ((const float4*)(Wo + C))[c4];
        float4 u = ((const float4*)ctr[pp])[c4];
        ct += (bb.x - a.x) * u.x + (bb.y - a.y) * u.y +
              (bb.z - a.z) * u.z + (bb.w - a.w) * u.w;
      }
      #pragma unroll
      for (int k = 0; k < KNB; ++k) h[po][k] = ct;
    }
    for (int c4 = 0; c4 < C / 4; ++c4) {
      float4 wv[PO];
      #pragma unroll
      for (int po = 0; po < PO; ++po)
        wv[po] = ((const float4*)(W + (size_t)(po * TPP + tpp) * 2 * C))[c4];
      #pragma unroll
      for (int k = 0; k < KNB; ++k) {
        float4 v = ((const float4*)nbr[pp][k])[c4];
        #pragma unroll
        for (int po = 0; po < PO; ++po) {
          h[po][k] += wv[po].x * v.x + wv[po].y * v.y +
                      wv[po].z * v.z + wv[po].w * v.w;
        }
      }
    }
  } else {
    #pragma unroll
    for (int po = 0; po < PO; ++po) {
      const int o = po * TPP + tpp;
      const float* Wo = W + (size_t)o * 2 * C;
      float w0 = Wo[0], w1 = Wo[1], w2 = Wo[2];
      float ct = (Wo[C + 0] - w0) * ctr[pp][0] +
                 (Wo[C + 1] - w1) * ctr[pp][1] +
                 (Wo[C + 2] - w2) * ctr[pp][2];
      #pragma unroll
      for (int k = 0; k < KNB; ++k) {
        h[po][k] = ct + w0 * nbr[pp][k][0] + w1 * nbr[pp][k][1] +
                   w2 * nbr[pp][k][2];
      }
    }
  }

  #pragma unroll
  for (int po = 0; po < PO; ++po) {
    const int o = po * TPP + tpp;
    float hmax = NEG_INF;
    #pragma unroll
    for (int k = 0; k < KNB; ++k) hmax = fmaxf(hmax, h[po][k]);
    float gg = bnp[o], be = bnp[O + o], mm = bnp[2 * O + o], vv = bnp[3 * O + o];
    float s = gg / sqrtf(vv + EPS_BN);
    float y = (hmax - mm) * s + be;
    Y[((size_t)b * NPTS + n0 + pp) * ldy + yoff + o] = (y > 0.f) ? y : 0.2f * y;
  }
}

// ---------------------------------------------------------------------------
// x5 v2: register-tiled 4 rows x 4 outs per thread. Per c4: 4 broadcast
// ds_read + 4 W loads + 64 fmac -> VALU-bound (old: 16 ds vs 64 fmac,
// LDS-issue-bound). BN+act before per-thread max/sum; 4-way LDS combine.
// ---------------------------------------------------------------------------
__global__ __launch_bounds__(256) void x5_kernel(
    const float* __restrict__ XC,   // [B][N][512]
    const float* __restrict__ W5,   // [1024][512]
    const float* __restrict__ bnp,  // [4][1024]
    float* __restrict__ pmax,       // [B][128][1024]
    float* __restrict__ psum) {
  const int b = blockIdx.y, tile = blockIdx.x;
  const int t0 = tile * 16;
  const int tid = threadIdx.x;
  const int rg = tid >> 6, ow = tid & 63;
  __shared__ float rows[16][512];
  __shared__ float redm[4][4][64];
  __shared__ float reds[4][4][64];

  for (int t = tid; t < 16 * 128; t += 256) {
    int i = t >> 7, c4 = t & 127;
    ((float4*)rows[i])[c4] =
        ((const float4*)(XC + ((size_t)b * NPTS + t0 + i) * 512))[c4];
  }
  __syncthreads();

  for (int og = 0; og < 4; ++og) {
    float acc[4][4];  // [row i][out j]
    #pragma unroll
    for (int i = 0; i < 4; ++i)
      #pragma unroll
      for (int j = 0; j < 4; ++j) acc[i][j] = 0.f;

    for (int c4 = 0; c4 < 128; ++c4) {
      float4 wv[4];
      #pragma unroll
      for (int j = 0; j < 4; ++j)
        wv[j] = ((const float4*)(W5 + (size_t)(og * 256 + ow + 64 * j) * 512))[c4];
      float4 r[4];
      #pragma unroll
      for (int i = 0; i < 4; ++i)
        r[i] = ((const float4*)rows[rg * 4 + i])[c4];  // broadcast
      #pragma unroll
      for (int i = 0; i < 4; ++i)
        #pragma unroll
        for (int j = 0; j < 4; ++j)
          acc[i][j] += wv[j].x * r[i].x + wv[j].y * r[i].y +
                       wv[j].z * r[i].z + wv[j].w * r[i].w;
    }

    #pragma unroll
    for (int j = 0; j < 4; ++j) {
      const int o = og * 256 + ow + 64 * j;
      float gg = bnp[o], be = bnp[1024 + o], mm = bnp[2048 + o], vv = bnp[3072 + o];
      float s = gg / sqrtf(vv + EPS_BN);
      float vm = NEG_INF, vs = 0.f;
      #pragma unroll
      for (int i = 0; i < 4; ++i) {
        float y = (acc[i][j] - mm) * s + be;
        y = (y > 0.f) ? y : 0.2f * y;
        vm = fmaxf(vm, y);
        vs += y;
      }
      redm[rg][j][ow] = vm;
      reds[rg][j][ow] = vs;
    }
    __syncthreads();
    if (rg == 0) {
      #pragma unroll
      for (int j = 0; j < 4; ++j) {
        float vm = redm[0][j][ow], vs = reds[0][j][ow];
        vm = fmaxf(vm, redm[1][j][ow]); vs += reds[1][j][ow];
        vm = fmaxf(vm, redm[2][j][ow]); vs += reds[2][j][ow];
        vm = fmaxf(vm, redm[3][j][ow]); vs += reds[3][j][ow];
        const int o = og * 256 + ow + 64 * j;
        pmax[((size_t)b * 128 + tile) * 1024 + o] = vm;
        psum[((size_t)b * 128 + tile) * 1024 + o] = vs;
      }
    }
    __syncthreads();
  }
}

__global__ void x5_reduce_final(const float* __restrict__ pmax,
                                const float* __restrict__ psum,
                                float* __restrict__ g) {  // [B][2048]: max|mean
  const int b = blockIdx.y;
  const int o = blockIdx.x * 256 + threadIdx.x;
  float vmax = NEG_INF, vsum = 0.f;
  for (int t = 0; t < 128; ++t) {
    vmax = fmaxf(vmax, pmax[((size_t)b * 128 + t) * 1024 + o]);
    vsum += psum[((size_t)b * 128 + t) * 1024 + o];
  }
  g[(size_t)b * 2048 + o] = vmax;
  g[(size_t)b * 2048 + 1024 + o] = vsum * (1.f / 2048.f);
}

// ---------------------------------------------------------------------------
// Final MLP (tiny; B=8 blocks each)
// ---------------------------------------------------------------------------
__global__ void mlp1_kernel(const float* __restrict__ g, const float* __restrict__ W, // [512][2048]
                            const float* __restrict__ bnp, float* __restrict__ h1) {
  const int b = blockIdx.x, tid = threadIdx.x; // 512 threads
  __shared__ float row[2048];
  for (int c = tid; c < 2048; c += 512) row[c] = g[(size_t)b * 2048 + c];
  __syncthreads();
  const float4* w = (const float4*)(W + (size_t)tid * 2048);
  float acc = 0.f;
  for (int c4 = 0; c4 < 512; ++c4) {
    float4 wv = w[c4], rv = ((const float4*)row)[c4];
    acc += wv.x * rv.x + wv.y * rv.y + wv.z * rv.z + wv.w * rv.w;
  }
  float gg = bnp[tid], be = bnp[512 + tid], mm = bnp[1024 + tid], vv = bnp[1536 + tid];
  float y = (acc - mm) * (gg / sqrtf(vv + EPS_BN)) + be;
  h1[(size_t)b * 512 + tid] = (y > 0.f) ? y : 0.2f * y;
}

__global__ void mlp2_kernel(const float* __restrict__ h1, const float* __restrict__ W, // [256][512]
                            const float* __restrict__ bl, const float* __restrict__ bnp,
                            float* __restrict__ h2) {
  const int b = blockIdx.x, tid = threadIdx.x; // 256 threads
  __shared__ float row[512];
  for (int c = tid; c < 512; c += 256) row[c] = h1[(size_t)b * 512 + c];
  __syncthreads();
  const float4* w = (const float4*)(W + (size_t)tid * 512);
  float acc = 0.f;
  for (int c4 = 0; c4 < 128; ++c4) {
    float4 wv = w[c4], rv = ((const float4*)row)[c4];
    acc += wv.x * rv.x + wv.y * rv.y + wv.z * rv.z + wv.w * rv.w;
  }
  acc += bl[tid];
  float gg = bnp[tid], be = bnp[256 + tid], mm = bnp[512 + tid], vv = bnp[768 + tid];
  float y = (acc - mm) * (gg / sqrtf(vv + EPS_BN)) + be;
  h2[(size_t)b * 256 + tid] = (y > 0.f) ? y : 0.2f * y;
}

__global__ void mlp3_kernel(const float* __restrict__ h2, const float* __restrict__ W, // [40][256]
                            const float* __restrict__ bl, float* __restrict__ out) {
  const int b = blockIdx.x, tid = threadIdx.x; // 64 threads
  __shared__ float row[256];
  for (int c = tid; c < 256; c += 64) row[c] = h2[(size_t)b * 256 + c];
  __syncthreads();
  if (tid < 40) {
    float acc = 0.f;
    for (int c = 0; c < 256; ++c) acc += W[tid * 256 + c] * row[c];
    out[(size_t)b * 40 + tid] = acc + bl[tid];
  }
}

// ---------------------------------------------------------------------------
extern "C" void kernel_launch(void* const* d_in, const int* in_sizes, int n_in,
                              void* d_out, int out_size, void* d_ws, size_t ws_size,
                              hipStream_t stream) {
  const float* x   = (const float*)d_in[0];
  // d_in[1] = normal (unused on this path)
  const float* w1  = (const float*)d_in[2];
  const float* w2  = (const float*)d_in[3];
  const float* w3  = (const float*)d_in[4];
  const float* w4  = (const float*)d_in[5];
  const float* w5  = (const float*)d_in[6];
  const float* wl1 = (const float*)d_in[7];
  const float* wl2 = (const float*)d_in[8];
  const float* bl2 = (const float*)d_in[9];
  const float* wl3 = (const float*)d_in[10];
  const float* bl3 = (const float*)d_in[11];
  const float* bn1 = (const float*)d_in[12];
  const float* bn2 = (const float*)d_in[13];
  const float* bn3 = (const float*)d_in[14];
  const float* bn4 = (const float*)d_in[15];
  const float* bn5 = (const float*)d_in[16];
  const float* bn6 = (const float*)d_in[17];
  const float* bn7 = (const float*)d_in[18];
  float* out = (float*)d_out;

  char* ws = (char*)d_ws;
  // xc: [8][2048][512] f32 = 32 MiB (holds x1|x2|x3|x4 channel slices)
  float* xc   = (float*)(ws);
  int*   idx  = (int*)  (ws + 33554432);             // [8][2048][20]  = 1.25 MiB
  float* pmax = (float*)(ws + 33554432 + 1310720);   // [8][128][1024] = 4 MiB
  float* psum = (float*)(ws + 33554432 + 1310720 + 4194304);
  float* g    = (float*)(ws + 33554432 + 1310720 + 8388608);          // [8][2048]
  float* h1   = (float*)(ws + 33554432 + 1310720 + 8388608 + 65536);  // [8][512]
  float* h2   = (float*)(ws + 33554432 + 1310720 + 8388608 + 65536 + 16384); // [8][256]

  dim3 gridKNN(NPTS / TQ, 8);
  dim3 gridPT(NPTS, 8);

  // EdgeConv 1: x[.,.,3] -> xc[:, :, 0:64]   (old template, tiny)
  knn_kernel<3><<<gridKNN, 256, 0, stream>>>(x, 3, 0, idx);
  edgeconv_tiled<3, 64, 4, 1><<<dim3(NPTS / 4, 8), 256, 0, stream>>>(
      x, 3, 0, idx, w1, bn1, xc, 512, 0);
  // EdgeConv 2: x1 -> xc[:, :, 64:128]
  knn_kernel<64><<<gridKNN, 256, 0, stream>>>(xc, 512, 0, idx);
  edgeconv_pt<64, 64, 1><<<gridPT, 256, 0, stream>>>(
      xc, 512, 0, idx, w2, bn2, xc, 512, 64);
  // EdgeConv 3: x2 -> xc[:, :, 128:256]
  knn_kernel<64><<<gridKNN, 256, 0, stream>>>(xc, 512, 64, idx);
  edgeconv_pt<64, 128, 2><<<gridPT, 256, 0, stream>>>(
      xc, 512, 64, idx, w3, bn3, xc, 512, 128);
  // EdgeConv 4: x3 -> xc[:, :, 256:512]
  knn_kernel<128><<<gridKNN, 256, 0, stream>>>(xc, 512, 128, idx);
  edgeconv_pt<128, 256, 4><<<gridPT, 256, 0, stream>>>(
      xc, 512, 128, idx, w4, bn4, xc, 512, 256);

  // x5 GEMM + bn + act + fused partial max/mean
  x5_kernel<<<dim3(128, 8), 256, 0, stream>>>(xc, w5, bn5, pmax, psum);
  x5_reduce_final<<<dim3(4, 8), 256, 0, stream>>>(pmax, psum, g);

  // Final MLP
  mlp1_kernel<<<8, 512, 0, stream>>>(g, wl1, bn6, h1);
  mlp2_kernel<<<8, 256, 0, stream>>>(h1, wl2, bl2, bn7, h2);
  mlp3_kernel<<<8, 64, 0, stream>>>(h2, wl3, bl3, out);
}

// Round 13
// 5465.374 us; speedup vs baseline: 2.2977x; 2.2977x over previous
//
#include <hip/hip_runtime.h>
#include <math.h>

#define EPS_BN 1e-5f
#define NEG_INF (-1e30f)

constexpr int NPTS = 2048;
constexpr int KNB = 20;
constexpr int TQ = 8;   // queries per kNN block

// ---------------------------------------------------------------------------
// Tiled kNN (validated R7): one block per (b, 8 queries). Distance-phase float
// accumulation order EXACTLY preserved (self-distance exactly 0; top-k order
// isomorphic to lax.top_k). DO NOT change this code path.
// ---------------------------------------------------------------------------
template<int C>
__global__ __launch_bounds__(256) void knn_kernel(const float* __restrict__ X,
                                                  int ld, int coff,
                                                  int* __restrict__ idx) {
  constexpr int CP = (C < 4) ? 4 : C;
  const int qt = blockIdx.x, b = blockIdx.y;
  const int q0 = qt * TQ;
  const int tid = threadIdx.x;
  const float* Xb = X + (size_t)b * NPTS * ld + coff;

  __shared__ float xq[TQ][CP];
  __shared__ float d2q[TQ];
  __shared__ float pd[TQ][NPTS];
  __shared__ unsigned long long cands[TQ][4 * KNB];

  for (int t = tid; t < TQ * C; t += 256) {
    int q = t / C, c = t - q * C;
    xq[q][c] = Xb[(size_t)(q0 + q) * ld + c];
  }
  __syncthreads();

  if (tid < TQ) {
    float d2n = 0.f;
    if constexpr (C % 4 == 0) {
      const float4* u4 = (const float4*)xq[tid];
      for (int c4 = 0; c4 < C / 4; ++c4) {
        float4 u = u4[c4];
        d2n += u.x * u.x; d2n += u.y * u.y; d2n += u.z * u.z; d2n += u.w * u.w;
      }
    } else {
      #pragma unroll
      for (int c = 0; c < C; ++c) d2n += xq[tid][c] * xq[tid][c];
    }
    d2q[tid] = d2n;
  }
  __syncthreads();

  for (int m = tid; m < NPTS; m += 256) {
    const float* xm = Xb + (size_t)m * ld;
    float dot[TQ];
    #pragma unroll
    for (int q = 0; q < TQ; ++q) dot[q] = 0.f;
    float d2m = 0.f;
    if constexpr (C % 4 == 0) {
      const float4* xm4 = (const float4*)xm;
      for (int c4 = 0; c4 < C / 4; ++c4) {
        float4 v = xm4[c4];
        d2m += v.x * v.x; d2m += v.y * v.y; d2m += v.z * v.z; d2m += v.w * v.w;
        #pragma unroll
        for (int q = 0; q < TQ; ++q) {
          float4 u = ((const float4*)xq[q])[c4];
          dot[q] += u.x * v.x; dot[q] += u.y * v.y;
          dot[q] += u.z * v.z; dot[q] += u.w * v.w;
        }
      }
    } else {
      float r[CP];
      #pragma unroll
      for (int c = 0; c < C; ++c) { r[c] = xm[c]; d2m += r[c] * r[c]; }
      #pragma unroll
      for (int q = 0; q < TQ; ++q) {
        #pragma unroll
        for (int c = 0; c < C; ++c) dot[q] += xq[q][c] * r[c];
      }
    }
    #pragma unroll
    for (int q = 0; q < TQ; ++q) pd[q][m] = 2.f * dot[q] - d2q[q] - d2m;
  }
  __syncthreads();

  const int w = tid >> 6, lane = tid & 63;
  for (int q = 0; q < TQ; ++q) {
    unsigned long long key[8];
    #pragma unroll
    for (int r = 0; r < 8; ++r) {
      const int m = (w << 9) + (r << 6) + lane;
      unsigned int u = __float_as_uint(pd[q][m]);
      u = (u & 0x80000000u) ? ~u : (u | 0x80000000u);  // monotone float->uint
      key[r] = ((unsigned long long)u << 32) |
               (unsigned long long)(0xFFFFFFFFu - (unsigned int)m);
    }
    unsigned long long prev = ~0ull;
    for (int k = 0; k < KNB; ++k) {
      unsigned long long best = 0ull;
      #pragma unroll
      for (int r = 0; r < 8; ++r) {
        unsigned long long c = key[r];
        if (c < prev && c > best) best = c;
      }
      #pragma unroll
      for (int off = 32; off > 0; off >>= 1) {
        unsigned long long o = __shfl_xor(best, off, 64);
        if (o > best) best = o;
      }
      if (lane == 0) cands[q][w * KNB + k] = best;
      prev = best;
    }
  }
  __syncthreads();

  for (int q = w; q < TQ; q += 4) {
    unsigned long long a = cands[q][lane];
    unsigned long long bq = (lane < 16) ? cands[q][64 + lane] : 0ull;
    int* out = idx + ((size_t)b * NPTS + q0 + q) * KNB;
    unsigned long long pv = ~0ull;
    for (int k = 0; k < KNB; ++k) {
      unsigned long long best = 0ull;
      if (a < pv && a > best) best = a;
      if (bq < pv && bq > best) best = bq;
      #pragma unroll
      for (int off = 32; off > 0; off >>= 1) {
        unsigned long long o = __shfl_xor(best, off, 64);
        if (o > best) best = o;
      }
      if (lane == 0)
        out[k] = (int)(0xFFFFFFFFu - (unsigned int)(best & 0xFFFFFFFFull));
      pv = best;
    }
  }
}

// ---------------------------------------------------------------------------
// edgeconv_gather: R11 body with nbr LDS staging DELETED -- neighbor rows are
// read directly from global inside the compute loop. Within a wave all lanes
// share the point pp (TPP>=64 for ec3/ec4), so each nbr float4 read is a
// wave-uniform address = single L2/L3 transaction broadcast. LDS drops
// 22KB -> ~2KB (occupancy was the R11 limiter: ec2=ec3=ec4=1000us despite
// 16:4:1 FLOPs). Offsets hoisted to 20 int regs; accumulation order is
// bitwise-identical to R11 (h[po][k]=ct then += dot4 per ascending c4).
// ---------------------------------------------------------------------------
template<int C, int O, int PT, int PO>
__global__ __launch_bounds__(PT * (O / PO)) void edgeconv_gather(
    const float* __restrict__ X, int ldx, int coff,
    const int* __restrict__ idx,
    const float* __restrict__ W,   // [O][2C]
    const float* __restrict__ bnp, // [4][O]
    float* __restrict__ Y, int ldy, int yoff) {
  static_assert(C % 4 == 0, "C multiple of 4");
  constexpr int TPP = O / PO;
  constexpr int NT = PT * TPP;
  const int n0 = blockIdx.x * PT, b = blockIdx.y;
  const int tid = threadIdx.x;
  const float* Xb = X + (size_t)b * NPTS * ldx + coff;

  __shared__ float ctr[PT][C];
  __shared__ int ids[PT][KNB];

  for (int t = tid; t < PT * KNB; t += NT) {
    int p = t / KNB, k = t - p * KNB;
    ids[p][k] = idx[((size_t)b * NPTS + n0 + p) * KNB + k];
  }
  for (int t = tid; t < PT * C; t += NT) {
    int p = t / C, c = t - p * C;
    ctr[p][c] = Xb[(size_t)(n0 + p) * ldx + c];
  }
  __syncthreads();

  const int pp = tid / TPP;
  const int tpp = tid - pp * TPP;

  // hoist neighbor row offsets (elements) into registers
  int offs[KNB];
  #pragma unroll
  for (int k = 0; k < KNB; ++k) offs[k] = ids[pp][k] * ldx;

  float h[PO][KNB];

  #pragma unroll
  for (int po = 0; po < PO; ++po) {
    const int o = po * TPP + tpp;
    const float* Wo = W + (size_t)o * 2 * C;
    float ct = 0.f;
    for (int c4 = 0; c4 < C / 4; ++c4) {
      float4 a = ((const float4*)Wo)[c4];
      float4 bb = ((const float4*)(Wo + C))[c4];
      float4 u = ((const float4*)ctr[pp])[c4];
      ct += (bb.x - a.x) * u.x + (bb.y - a.y) * u.y +
            (bb.z - a.z) * u.z + (bb.w - a.w) * u.w;
    }
    #pragma unroll
    for (int k = 0; k < KNB; ++k) h[po][k] = ct;
  }

  for (int c4 = 0; c4 < C / 4; ++c4) {
    float4 wv[PO];
    #pragma unroll
    for (int po = 0; po < PO; ++po)
      wv[po] = ((const float4*)(W + (size_t)(po * TPP + tpp) * 2 * C))[c4];
    #pragma unroll
    for (int k = 0; k < KNB; ++k) {
      float4 v = ((const float4*)(Xb + offs[k]))[c4];  // wave-uniform broadcast
      #pragma unroll
      for (int po = 0; po < PO; ++po) {
        h[po][k] += wv[po].x * v.x + wv[po].y * v.y +
                    wv[po].z * v.z + wv[po].w * v.w;
      }
    }
  }

  #pragma unroll
  for (int po = 0; po < PO; ++po) {
    const int o = po * TPP + tpp;
    float hmax = NEG_INF;
    #pragma unroll
    for (int k = 0; k < KNB; ++k) hmax = fmaxf(hmax, h[po][k]);
    float gg = bnp[o], be = bnp[O + o], mm = bnp[2 * O + o], vv = bnp[3 * O + o];
    float s = gg / sqrtf(vv + EPS_BN);
    float y = (hmax - mm) * s + be;
    Y[((size_t)b * NPTS + n0 + pp) * ldy + yoff + o] = (y > 0.f) ? y : 0.2f * y;
  }
}

// ---------------------------------------------------------------------------
// Old tiled EdgeConv (validated) -- kept for the C==3 layer only.
// ---------------------------------------------------------------------------
template<int C, int O, int PT, int PO>
__global__ __launch_bounds__(PT * (O / PO)) void edgeconv_tiled(
    const float* __restrict__ X, int ldx, int coff,
    const int* __restrict__ idx,
    const float* __restrict__ W,   // [O][2C]
    const float* __restrict__ bnp, // [4][O]
    float* __restrict__ Y, int ldy, int yoff) {
  constexpr int TPP = O / PO;
  constexpr int NT = PT * TPP;
  constexpr int CP = (C < 4) ? 4 : C;
  const int n0 = blockIdx.x * PT, b = blockIdx.y;
  const int tid = threadIdx.x;
  const float* Xb = X + (size_t)b * NPTS * ldx + coff;

  __shared__ float ctr[PT][CP];
  __shared__ float nbr[PT][KNB][CP];
  __shared__ int ids[PT][KNB];

  for (int t = tid; t < PT * KNB; t += NT) {
    int p = t / KNB, k = t - p * KNB;
    ids[p][k] = idx[((size_t)b * NPTS + n0 + p) * KNB + k];
  }
  for (int t = tid; t < PT * C; t += NT) {
    int p = t / C, c = t - p * C;
    ctr[p][c] = Xb[(size_t)(n0 + p) * ldx + c];
  }
  __syncthreads();
  for (int t = tid; t < PT * KNB * C; t += NT) {
    int p = t / (KNB * C), r = t - p * (KNB * C);
    int k = r / C, c = r - k * C;
    nbr[p][k][c] = Xb[(size_t)ids[p][k] * ldx + c];
  }
  __syncthreads();

  const int pp = tid / TPP;
  const int tpp = tid - pp * TPP;

  float h[PO][KNB];

  if constexpr (C % 4 == 0) {
    #pragma unroll
    for (int po = 0; po < PO; ++po) {
      const int o = po * TPP + tpp;
      const float* Wo = W + (size_t)o * 2 * C;
      float ct = 0.f;
      for (int c4 = 0; c4 < C / 4; ++c4) {
        float4 a = ((const float4*)Wo)[c4];
        float4 bb = ((const float4*)(Wo + C))[c4];
        float4 u = ((const float4*)ctr[pp])[c4];
        ct += (bb.x - a.x) * u.x + (bb.y - a.y) * u.y +
              (bb.z - a.z) * u.z + (bb.w - a.w) * u.w;
      }
      #pragma unroll
      for (int k = 0; k < KNB; ++k) h[po][k] = ct;
    }
    for (int c4 = 0; c4 < C / 4; ++c4) {
      float4 wv[PO];
      #pragma unroll
      for (int po = 0; po < PO; ++po)
        wv[po] = ((const float4*)(W + (size_t)(po * TPP + tpp) * 2 * C))[c4];
      #pragma unroll
      for (int k = 0; k < KNB; ++k) {
        float4 v = ((const float4*)nbr[pp][k])[c4];
        #pragma unroll
        for (int po = 0; po < PO; ++po) {
          h[po][k] += wv[po].x * v.x + wv[po].y * v.y +
                      wv[po].z * v.z + wv[po].w * v.w;
        }
      }
    }
  } else {
    #pragma unroll
    for (int po = 0; po < PO; ++po) {
      const int o = po * TPP + tpp;
      const float* Wo = W + (size_t)o * 2 * C;
      float w0 = Wo[0], w1 = Wo[1], w2 = Wo[2];
      float ct = (Wo[C + 0] - w0) * ctr[pp][0] +
                 (Wo[C + 1] - w1) * ctr[pp][1] +
                 (Wo[C + 2] - w2) * ctr[pp][2];
      #pragma unroll
      for (int k = 0; k < KNB; ++k) {
        h[po][k] = ct + w0 * nbr[pp][k][0] + w1 * nbr[pp][k][1] +
                   w2 * nbr[pp][k][2];
      }
    }
  }

  #pragma unroll
  for (int po = 0; po < PO; ++po) {
    const int o = po * TPP + tpp;
    float hmax = NEG_INF;
    #pragma unroll
    for (int k = 0; k < KNB; ++k) hmax = fmaxf(hmax, h[po][k]);
    float gg = bnp[o], be = bnp[O + o], mm = bnp[2 * O + o], vv = bnp[3 * O + o];
    float s = gg / sqrtf(vv + EPS_BN);
    float y = (hmax - mm) * s + be;
    Y[((size_t)b * NPTS + n0 + pp) * ldy + yoff + o] = (y > 0.f) ? y : 0.2f * y;
  }
}

// ---------------------------------------------------------------------------
// x5 (validated R7-R11): 16 rows staged in LDS; thread computes 4 outputs.
// ---------------------------------------------------------------------------
__global__ void x5_kernel(const float* __restrict__ XC,   // [B][N][512]
                          const float* __restrict__ W5,   // [1024][512]
                          const float* __restrict__ bnp,  // [4][1024]
                          float* __restrict__ pmax,       // [B][128][1024]
                          float* __restrict__ psum) {
  const int b = blockIdx.y, tile = blockIdx.x;
  const int t0 = tile * 16;
  const int tid = threadIdx.x;
  __shared__ float rows[16][512];
  for (int t = tid; t < 16 * 512; t += 256) {
    int i = t >> 9, c = t & 511;
    rows[i][c] = XC[((size_t)b * NPTS + t0 + i) * 512 + c];
  }
  __syncthreads();
  for (int og = 0; og < 4; ++og) {
    const int o = og * 256 + tid;
    const float4* w = (const float4*)(W5 + (size_t)o * 512);
    float acc[16];
    #pragma unroll
    for (int i = 0; i < 16; ++i) acc[i] = 0.f;
    for (int c4 = 0; c4 < 128; ++c4) {
      float4 wv = w[c4];
      #pragma unroll
      for (int i = 0; i < 16; ++i) {
        float4 r = ((const float4*)rows[i])[c4];
        acc[i] += wv.x * r.x + wv.y * r.y + wv.z * r.z + wv.w * r.w;
      }
    }
    float gg = bnp[o], be = bnp[1024 + o], mm = bnp[2048 + o], vv = bnp[3072 + o];
    float s = gg / sqrtf(vv + EPS_BN);
    float vmax = NEG_INF, vsum = 0.f;
    #pragma unroll
    for (int i = 0; i < 16; ++i) {
      float y = (acc[i] - mm) * s + be;
      y = (y > 0.f) ? y : 0.2f * y;
      vmax = fmaxf(vmax, y);
      vsum += y;
    }
    pmax[((size_t)b * 128 + tile) * 1024 + o] = vmax;
    psum[((size_t)b * 128 + tile) * 1024 + o] = vsum;
  }
}

__global__ void x5_reduce_final(const float* __restrict__ pmax,
                                const float* __restrict__ psum,
                                float* __restrict__ g) {  // [B][2048]: max|mean
  const int b = blockIdx.y;
  const int o = blockIdx.x * 256 + threadIdx.x;
  float vmax = NEG_INF, vsum = 0.f;
  for (int t = 0; t < 128; ++t) {
    vmax = fmaxf(vmax, pmax[((size_t)b * 128 + t) * 1024 + o]);
    vsum += psum[((size_t)b * 128 + t) * 1024 + o];
  }
  g[(size_t)b * 2048 + o] = vmax;
  g[(size_t)b * 2048 + 1024 + o] = vsum * (1.f / 2048.f);
}

// ---------------------------------------------------------------------------
// Final MLP (tiny; B=8 blocks each)
// ---------------------------------------------------------------------------
__global__ void mlp1_kernel(const float* __restrict__ g, const float* __restrict__ W, // [512][2048]
                            const float* __restrict__ bnp, float* __restrict__ h1) {
  const int b = blockIdx.x, tid = threadIdx.x; // 512 threads
  __shared__ float row[2048];
  for (int c = tid; c < 2048; c += 512) row[c] = g[(size_t)b * 2048 + c];
  __syncthreads();
  const float4* w = (const float4*)(W + (size_t)tid * 2048);
  float acc = 0.f;
  for (int c4 = 0; c4 < 512; ++c4) {
    float4 wv = w[c4], rv = ((const float4*)row)[c4];
    acc += wv.x * rv.x + wv.y * rv.y + wv.z * rv.z + wv.w * rv.w;
  }
  float gg = bnp[tid], be = bnp[512 + tid], mm = bnp[1024 + tid], vv = bnp[1536 + tid];
  float y = (acc - mm) * (gg / sqrtf(vv + EPS_BN)) + be;
  h1[(size_t)b * 512 + tid] = (y > 0.f) ? y : 0.2f * y;
}

__global__ void mlp2_kernel(const float* __restrict__ h1, const float* __restrict__ W, // [256][512]
                            const float* __restrict__ bl, const float* __restrict__ bnp,
                            float* __restrict__ h2) {
  const int b = blockIdx.x, tid = threadIdx.x; // 256 threads
  __shared__ float row[512];
  for (int c = tid; c < 512; c += 256) row[c] = h1[(size_t)b * 512 + c];
  __syncthreads();
  const float4* w = (const float4*)(W + (size_t)tid * 512);
  float acc = 0.f;
  for (int c4 = 0; c4 < 128; ++c4) {
    float4 wv = w[c4], rv = ((const float4*)row)[c4];
    acc += wv.x * rv.x + wv.y * rv.y + wv.z * rv.z + wv.w * rv.w;
  }
  acc += bl[tid];
  float gg = bnp[tid], be = bnp[256 + tid], mm = bnp[512 + tid], vv = bnp[768 + tid];
  float y = (acc - mm) * (gg / sqrtf(vv + EPS_BN)) + be;
  h2[(size_t)b * 256 + tid] = (y > 0.f) ? y : 0.2f * y;
}

__global__ void mlp3_kernel(const float* __restrict__ h2, const float* __restrict__ W, // [40][256]
                            const float* __restrict__ bl, float* __restrict__ out) {
  const int b = blockIdx.x, tid = threadIdx.x; // 64 threads
  __shared__ float row[256];
  for (int c = tid; c < 256; c += 64) row[c] = h2[(size_t)b * 256 + c];
  __syncthreads();
  if (tid < 40) {
    float acc = 0.f;
    for (int c = 0; c < 256; ++c) acc += W[tid * 256 + c] * row[c];
    out[(size_t)b * 40 + tid] = acc + bl[tid];
  }
}

// ---------------------------------------------------------------------------
extern "C" void kernel_launch(void* const* d_in, const int* in_sizes, int n_in,
                              void* d_out, int out_size, void* d_ws, size_t ws_size,
                              hipStream_t stream) {
  const float* x   = (const float*)d_in[0];
  // d_in[1] = normal (unused on this path)
  const float* w1  = (const float*)d_in[2];
  const float* w2  = (const float*)d_in[3];
  const float* w3  = (const float*)d_in[4];
  const float* w4  = (const float*)d_in[5];
  const float* w5  = (const float*)d_in[6];
  const float* wl1 = (const float*)d_in[7];
  const float* wl2 = (const float*)d_in[8];
  const float* bl2 = (const float*)d_in[9];
  const float* wl3 = (const float*)d_in[10];
  const float* bl3 = (const float*)d_in[11];
  const float* bn1 = (const float*)d_in[12];
  const float* bn2 = (const float*)d_in[13];
  const float* bn3 = (const float*)d_in[14];
  const float* bn4 = (const float*)d_in[15];
  const float* bn5 = (const float*)d_in[16];
  const float* bn6 = (const float*)d_in[17];
  const float* bn7 = (const float*)d_in[18];
  float* out = (float*)d_out;

  char* ws = (char*)d_ws;
  // xc: [8][2048][512] f32 = 32 MiB (holds x1|x2|x3|x4 channel slices)
  float* xc   = (float*)(ws);
  int*   idx  = (int*)  (ws + 33554432);             // [8][2048][20]  = 1.25 MiB
  float* pmax = (float*)(ws + 33554432 + 1310720);   // [8][128][1024] = 4 MiB
  float* psum = (float*)(ws + 33554432 + 1310720 + 4194304);
  float* g    = (float*)(ws + 33554432 + 1310720 + 8388608);          // [8][2048]
  float* h1   = (float*)(ws + 33554432 + 1310720 + 8388608 + 65536);  // [8][512]
  float* h2   = (float*)(ws + 33554432 + 1310720 + 8388608 + 65536 + 16384); // [8][256]

  dim3 gridKNN(NPTS / TQ, 8);

  // EdgeConv 1: x[.,.,3] -> xc[:, :, 0:64]   (old template, tiny LDS)
  knn_kernel<3><<<gridKNN, 256, 0, stream>>>(x, 3, 0, idx);
  edgeconv_tiled<3, 64, 4, 1><<<dim3(NPTS / 4, 8), 256, 0, stream>>>(
      x, 3, 0, idx, w1, bn1, xc, 512, 0);
  // EdgeConv 2: x1 -> xc[:, :, 64:128]       (gather, 128 thr)
  knn_kernel<64><<<gridKNN, 256, 0, stream>>>(xc, 512, 0, idx);
  edgeconv_gather<64, 64, 4, 2><<<dim3(NPTS / 4, 8), 128, 0, stream>>>(
      xc, 512, 0, idx, w2, bn2, xc, 512, 64);
  // EdgeConv 3: x2 -> xc[:, :, 128:256]      (gather, 256 thr)
  knn_kernel<64><<<gridKNN, 256, 0, stream>>>(xc, 512, 64, idx);
  edgeconv_gather<64, 128, 4, 2><<<dim3(NPTS / 4, 8), 256, 0, stream>>>(
      xc, 512, 64, idx, w3, bn3, xc, 512, 128);
  // EdgeConv 4: x3 -> xc[:, :, 256:512]      (gather, 256 thr)
  knn_kernel<128><<<gridKNN, 256, 0, stream>>>(xc, 512, 128, idx);
  edgeconv_gather<128, 256, 2, 2><<<dim3(NPTS / 2, 8), 256, 0, stream>>>(
      xc, 512, 128, idx, w4, bn4, xc, 512, 256);

  // x5 GEMM + bn + act + fused partial max/mean
  x5_kernel<<<dim3(128, 8), 256, 0, stream>>>(xc, w5, bn5, pmax, psum);
  x5_reduce_final<<<dim3(4, 8), 256, 0, stream>>>(pmax, psum, g);

  // Final MLP
  mlp1_kernel<<<8, 512, 0, stream>>>(g, wl1, bn6, h1);
  mlp2_kernel<<<8, 256, 0, stream>>>(h1, wl2, bl2, bn7, h2);
  mlp3_kernel<<<8, 64, 0, stream>>>(h2, wl3, bl3, out);
}

// Round 14
// 3999.941 us; speedup vs baseline: 3.1395x; 1.3664x over previous
//
#include <hip/hip_runtime.h>
#include <math.h>

#define EPS_BN 1e-5f
#define NEG_INF (-1e30f)

constexpr int NPTS = 2048;
constexpr int KNB = 20;
constexpr int TQ = 8;   // queries per kNN block

// ---------------------------------------------------------------------------
// Tiled kNN (validated R7): DO NOT change this code path.
// ---------------------------------------------------------------------------
template<int C>
__global__ __launch_bounds__(256) void knn_kernel(const float* __restrict__ X,
                                                  int ld, int coff,
                                                  int* __restrict__ idx) {
  constexpr int CP = (C < 4) ? 4 : C;
  const int qt = blockIdx.x, b = blockIdx.y;
  const int q0 = qt * TQ;
  const int tid = threadIdx.x;
  const float* Xb = X + (size_t)b * NPTS * ld + coff;

  __shared__ float xq[TQ][CP];
  __shared__ float d2q[TQ];
  __shared__ float pd[TQ][NPTS];
  __shared__ unsigned long long cands[TQ][4 * KNB];

  for (int t = tid; t < TQ * C; t += 256) {
    int q = t / C, c = t - q * C;
    xq[q][c] = Xb[(size_t)(q0 + q) * ld + c];
  }
  __syncthreads();

  if (tid < TQ) {
    float d2n = 0.f;
    if constexpr (C % 4 == 0) {
      const float4* u4 = (const float4*)xq[tid];
      for (int c4 = 0; c4 < C / 4; ++c4) {
        float4 u = u4[c4];
        d2n += u.x * u.x; d2n += u.y * u.y; d2n += u.z * u.z; d2n += u.w * u.w;
      }
    } else {
      #pragma unroll
      for (int c = 0; c < C; ++c) d2n += xq[tid][c] * xq[tid][c];
    }
    d2q[tid] = d2n;
  }
  __syncthreads();

  for (int m = tid; m < NPTS; m += 256) {
    const float* xm = Xb + (size_t)m * ld;
    float dot[TQ];
    #pragma unroll
    for (int q = 0; q < TQ; ++q) dot[q] = 0.f;
    float d2m = 0.f;
    if constexpr (C % 4 == 0) {
      const float4* xm4 = (const float4*)xm;
      for (int c4 = 0; c4 < C / 4; ++c4) {
        float4 v = xm4[c4];
        d2m += v.x * v.x; d2m += v.y * v.y; d2m += v.z * v.z; d2m += v.w * v.w;
        #pragma unroll
        for (int q = 0; q < TQ; ++q) {
          float4 u = ((const float4*)xq[q])[c4];
          dot[q] += u.x * v.x; dot[q] += u.y * v.y;
          dot[q] += u.z * v.z; dot[q] += u.w * v.w;
        }
      }
    } else {
      float r[CP];
      #pragma unroll
      for (int c = 0; c < C; ++c) { r[c] = xm[c]; d2m += r[c] * r[c]; }
      #pragma unroll
      for (int q = 0; q < TQ; ++q) {
        #pragma unroll
        for (int c = 0; c < C; ++c) dot[q] += xq[q][c] * r[c];
      }
    }
    #pragma unroll
    for (int q = 0; q < TQ; ++q) pd[q][m] = 2.f * dot[q] - d2q[q] - d2m;
  }
  __syncthreads();

  const int w = tid >> 6, lane = tid & 63;
  for (int q = 0; q < TQ; ++q) {
    unsigned long long key[8];
    #pragma unroll
    for (int r = 0; r < 8; ++r) {
      const int m = (w << 9) + (r << 6) + lane;
      unsigned int u = __float_as_uint(pd[q][m]);
      u = (u & 0x80000000u) ? ~u : (u | 0x80000000u);  // monotone float->uint
      key[r] = ((unsigned long long)u << 32) |
               (unsigned long long)(0xFFFFFFFFu - (unsigned int)m);
    }
    unsigned long long prev = ~0ull;
    for (int k = 0; k < KNB; ++k) {
      unsigned long long best = 0ull;
      #pragma unroll
      for (int r = 0; r < 8; ++r) {
        unsigned long long c = key[r];
        if (c < prev && c > best) best = c;
      }
      #pragma unroll
      for (int off = 32; off > 0; off >>= 1) {
        unsigned long long o = __shfl_xor(best, off, 64);
        if (o > best) best = o;
      }
      if (lane == 0) cands[q][w * KNB + k] = best;
      prev = best;
    }
  }
  __syncthreads();

  for (int q = w; q < TQ; q += 4) {
    unsigned long long a = cands[q][lane];
    unsigned long long bq = (lane < 16) ? cands[q][64 + lane] : 0ull;
    int* out = idx + ((size_t)b * NPTS + q0 + q) * KNB;
    unsigned long long pv = ~0ull;
    for (int k = 0; k < KNB; ++k) {
      unsigned long long best = 0ull;
      if (a < pv && a > best) best = a;
      if (bq < pv && bq > best) best = bq;
      #pragma unroll
      for (int off = 32; off > 0; off >>= 1) {
        unsigned long long o = __shfl_xor(best, off, 64);
        if (o > best) best = o;
      }
      if (lane == 0)
        out[k] = (int)(0xFFFFFFFFu - (unsigned int)(best & 0xFFFFFFFFull));
      pv = best;
    }
  }
}

// ---------------------------------------------------------------------------
// Weight transpose: W[R][CC] -> Wt[CC][R]. Tiny, runs once per launch.
// ---------------------------------------------------------------------------
__global__ void transpose_w(const float* __restrict__ in, float* __restrict__ out,
                            int R, int CC) {
  int t = blockIdx.x * 256 + threadIdx.x;
  if (t < R * CC) {
    int r = t / CC, c = t - r * CC;
    out[c * R + r] = in[t];
  }
}

// ---------------------------------------------------------------------------
// EdgeConv with TRANSPOSED weights Wt[2C][O]: W reads are lane-consecutive
// (coalesced, 4 transactions/load vs 64 for the old 1KB-strided row reads --
// the latency-stall source: every variant R7-R13 sat at ~1ms, VALU 30-41%,
// occupancy <=23%). LDS shrunk to ~11KB (PT halved) so 4-5 blocks fit even
// in a 64KB pool (R8/R11 occupancy fits 64KB: 43.5KB->1blk, 22KB->2blk).
// FMA order bitwise-identical to R11 (c ascending; h=ct then +=dot4).
// ---------------------------------------------------------------------------
template<int C, int O, int PT, int PO>
__global__ __launch_bounds__(PT * (O / PO)) void edgeconv_wt(
    const float* __restrict__ X, int ldx, int coff,
    const int* __restrict__ idx,
    const float* __restrict__ Wt,  // [2C][O] transposed
    const float* __restrict__ bnp, // [4][O]
    float* __restrict__ Y, int ldy, int yoff) {
  static_assert(C % 4 == 0, "C multiple of 4");
  constexpr int TPP = O / PO;
  constexpr int NT = PT * TPP;
  static_assert(NT % 64 == 0, "block multiple of wave");
  const int n0 = blockIdx.x * PT, b = blockIdx.y;
  const int tid = threadIdx.x;
  const float* Xb = X + (size_t)b * NPTS * ldx + coff;

  __shared__ float ctr[PT][C];
  __shared__ float nbr[PT][KNB][C];
  __shared__ int ids[PT][KNB];

  for (int t = tid; t < PT * KNB; t += NT) {
    int p = t / KNB, k = t - p * KNB;
    ids[p][k] = idx[((size_t)b * NPTS + n0 + p) * KNB + k];
  }
  for (int t = tid; t < PT * C; t += NT) {
    int p = t / C, c = t - p * C;
    ctr[p][c] = Xb[(size_t)(n0 + p) * ldx + c];
  }
  __syncthreads();
  for (int t = tid; t < PT * KNB * C; t += NT) {
    int p = t / (KNB * C), r = t - p * (KNB * C);
    int k = r / C, c = r - k * C;
    nbr[p][k][c] = Xb[(size_t)ids[p][k] * ldx + c];
  }
  __syncthreads();

  const int pp = tid / TPP;
  const int tpp = tid - pp * TPP;

  float h[PO][KNB];

  // cterm = dot(W2-W1, ctr); Wt[c][o]=W1[o][c], Wt[C+c][o]=W2[o][c]
  #pragma unroll
  for (int po = 0; po < PO; ++po) {
    const int o = po * TPP + tpp;
    float ct = 0.f;
    for (int c4 = 0; c4 < C / 4; ++c4) {
      const int c = 4 * c4;
      float4 u = ((const float4*)ctr[pp])[c4];
      ct += (Wt[(C + c + 0) * O + o] - Wt[(c + 0) * O + o]) * u.x +
            (Wt[(C + c + 1) * O + o] - Wt[(c + 1) * O + o]) * u.y +
            (Wt[(C + c + 2) * O + o] - Wt[(c + 2) * O + o]) * u.z +
            (Wt[(C + c + 3) * O + o] - Wt[(c + 3) * O + o]) * u.w;
    }
    #pragma unroll
    for (int k = 0; k < KNB; ++k) h[po][k] = ct;
  }

  for (int c4 = 0; c4 < C / 4; ++c4) {
    const int c = 4 * c4;
    float w0[PO], w1[PO], w2[PO], w3[PO];
    #pragma unroll
    for (int po = 0; po < PO; ++po) {
      const int o = po * TPP + tpp;
      w0[po] = Wt[(c + 0) * O + o];  // coalesced: lanes -> consecutive o
      w1[po] = Wt[(c + 1) * O + o];
      w2[po] = Wt[(c + 2) * O + o];
      w3[po] = Wt[(c + 3) * O + o];
    }
    #pragma unroll
    for (int k = 0; k < KNB; ++k) {
      float4 v = ((const float4*)nbr[pp][k])[c4];
      #pragma unroll
      for (int po = 0; po < PO; ++po) {
        h[po][k] += w0[po] * v.x + w1[po] * v.y + w2[po] * v.z + w3[po] * v.w;
      }
    }
  }

  #pragma unroll
  for (int po = 0; po < PO; ++po) {
    const int o = po * TPP + tpp;
    float hmax = NEG_INF;
    #pragma unroll
    for (int k = 0; k < KNB; ++k) hmax = fmaxf(hmax, h[po][k]);
    float gg = bnp[o], be = bnp[O + o], mm = bnp[2 * O + o], vv = bnp[3 * O + o];
    float s = gg / sqrtf(vv + EPS_BN);
    float y = (hmax - mm) * s + be;
    Y[((size_t)b * NPTS + n0 + pp) * ldy + yoff + o] = (y > 0.f) ? y : 0.2f * y;
  }
}

// ---------------------------------------------------------------------------
// Old tiled EdgeConv (validated) -- kept for the C==3 layer only.
// ---------------------------------------------------------------------------
template<int C, int O, int PT, int PO>
__global__ __launch_bounds__(PT * (O / PO)) void edgeconv_tiled(
    const float* __restrict__ X, int ldx, int coff,
    const int* __restrict__ idx,
    const float* __restrict__ W,   // [O][2C]
    const float* __restrict__ bnp, // [4][O]
    float* __restrict__ Y, int ldy, int yoff) {
  constexpr int TPP = O / PO;
  constexpr int NT = PT * TPP;
  constexpr int CP = (C < 4) ? 4 : C;
  const int n0 = blockIdx.x * PT, b = blockIdx.y;
  const int tid = threadIdx.x;
  const float* Xb = X + (size_t)b * NPTS * ldx + coff;

  __shared__ float ctr[PT][CP];
  __shared__ float nbr[PT][KNB][CP];
  __shared__ int ids[PT][KNB];

  for (int t = tid; t < PT * KNB; t += NT) {
    int p = t / KNB, k = t - p * KNB;
    ids[p][k] = idx[((size_t)b * NPTS + n0 + p) * KNB + k];
  }
  for (int t = tid; t < PT * C; t += NT) {
    int p = t / C, c = t - p * C;
    ctr[p][c] = Xb[(size_t)(n0 + p) * ldx + c];
  }
  __syncthreads();
  for (int t = tid; t < PT * KNB * C; t += NT) {
    int p = t / (KNB * C), r = t - p * (KNB * C);
    int k = r / C, c = r - k * C;
    nbr[p][k][c] = Xb[(size_t)ids[p][k] * ldx + c];
  }
  __syncthreads();

  const int pp = tid / TPP;
  const int tpp = tid - pp * TPP;

  float h[PO][KNB];

  #pragma unroll
  for (int po = 0; po < PO; ++po) {
    const int o = po * TPP + tpp;
    const float* Wo = W + (size_t)o * 2 * C;
    float w0 = Wo[0], w1 = Wo[1], w2 = Wo[2];
    float ct = (Wo[C + 0] - w0) * ctr[pp][0] +
               (Wo[C + 1] - w1) * ctr[pp][1] +
               (Wo[C + 2] - w2) * ctr[pp][2];
    #pragma unroll
    for (int k = 0; k < KNB; ++k) {
      h[po][k] = ct + w0 * nbr[pp][k][0] + w1 * nbr[pp][k][1] +
                 w2 * nbr[pp][k][2];
    }
  }

  #pragma unroll
  for (int po = 0; po < PO; ++po) {
    const int o = po * TPP + tpp;
    float hmax = NEG_INF;
    #pragma unroll
    for (int k = 0; k < KNB; ++k) hmax = fmaxf(hmax, h[po][k]);
    float gg = bnp[o], be = bnp[O + o], mm = bnp[2 * O + o], vv = bnp[3 * O + o];
    float s = gg / sqrtf(vv + EPS_BN);
    float y = (hmax - mm) * s + be;
    Y[((size_t)b * NPTS + n0 + pp) * ldy + yoff + o] = (y > 0.f) ? y : 0.2f * y;
  }
}

// ---------------------------------------------------------------------------
// x5 with transposed W5t[512][1024]: coalesced weight reads.
// ---------------------------------------------------------------------------
__global__ void x5_kernel(const float* __restrict__ XC,   // [B][N][512]
                          const float* __restrict__ W5t,  // [512][1024]
                          const float* __restrict__ bnp,  // [4][1024]
                          float* __restrict__ pmax,       // [B][128][1024]
                          float* __restrict__ psum) {
  const int b = blockIdx.y, tile = blockIdx.x;
  const int t0 = tile * 16;
  const int tid = threadIdx.x;
  __shared__ float rows[16][512];
  for (int t = tid; t < 16 * 512; t += 256) {
    int i = t >> 9, c = t & 511;
    rows[i][c] = XC[((size_t)b * NPTS + t0 + i) * 512 + c];
  }
  __syncthreads();
  for (int og = 0; og < 4; ++og) {
    const int o = og * 256 + tid;
    float acc[16];
    #pragma unroll
    for (int i = 0; i < 16; ++i) acc[i] = 0.f;
    for (int c4 = 0; c4 < 128; ++c4) {
      const int c = 4 * c4;
      float w0 = W5t[(size_t)(c + 0) * 1024 + o];  // coalesced
      float w1 = W5t[(size_t)(c + 1) * 1024 + o];
      float w2 = W5t[(size_t)(c + 2) * 1024 + o];
      float w3 = W5t[(size_t)(c + 3) * 1024 + o];
      #pragma unroll
      for (int i = 0; i < 16; ++i) {
        float4 r = ((const float4*)rows[i])[c4];
        acc[i] += w0 * r.x + w1 * r.y + w2 * r.z + w3 * r.w;
      }
    }
    float gg = bnp[o], be = bnp[1024 + o], mm = bnp[2048 + o], vv = bnp[3072 + o];
    float s = gg / sqrtf(vv + EPS_BN);
    float vmax = NEG_INF, vsum = 0.f;
    #pragma unroll
    for (int i = 0; i < 16; ++i) {
      float y = (acc[i] - mm) * s + be;
      y = (y > 0.f) ? y : 0.2f * y;
      vmax = fmaxf(vmax, y);
      vsum += y;
    }
    pmax[((size_t)b * 128 + tile) * 1024 + o] = vmax;
    psum[((size_t)b * 128 + tile) * 1024 + o] = vsum;
  }
}

__global__ void x5_reduce_final(const float* __restrict__ pmax,
                                const float* __restrict__ psum,
                                float* __restrict__ g) {  // [B][2048]: max|mean
  const int b = blockIdx.y;
  const int o = blockIdx.x * 256 + threadIdx.x;
  float vmax = NEG_INF, vsum = 0.f;
  for (int t = 0; t < 128; ++t) {
    vmax = fmaxf(vmax, pmax[((size_t)b * 128 + t) * 1024 + o]);
    vsum += psum[((size_t)b * 128 + t) * 1024 + o];
  }
  g[(size_t)b * 2048 + o] = vmax;
  g[(size_t)b * 2048 + 1024 + o] = vsum * (1.f / 2048.f);
}

// ---------------------------------------------------------------------------
// Final MLP (tiny; B=8 blocks each)
// ---------------------------------------------------------------------------
__global__ void mlp1_kernel(const float* __restrict__ g, const float* __restrict__ W, // [512][2048]
                            const float* __restrict__ bnp, float* __restrict__ h1) {
  const int b = blockIdx.x, tid = threadIdx.x; // 512 threads
  __shared__ float row[2048];
  for (int c = tid; c < 2048; c += 512) row[c] = g[(size_t)b * 2048 + c];
  __syncthreads();
  const float4* w = (const float4*)(W + (size_t)tid * 2048);
  float acc = 0.f;
  for (int c4 = 0; c4 < 512; ++c4) {
    float4 wv = w[c4], rv = ((const float4*)row)[c4];
    acc += wv.x * rv.x + wv.y * rv.y + wv.z * rv.z + wv.w * rv.w;
  }
  float gg = bnp[tid], be = bnp[512 + tid], mm = bnp[1024 + tid], vv = bnp[1536 + tid];
  float y = (acc - mm) * (gg / sqrtf(vv + EPS_BN)) + be;
  h1[(size_t)b * 512 + tid] = (y > 0.f) ? y : 0.2f * y;
}

__global__ void mlp2_kernel(const float* __restrict__ h1, const float* __restrict__ W, // [256][512]
                            const float* __restrict__ bl, const float* __restrict__ bnp,
                            float* __restrict__ h2) {
  const int b = blockIdx.x, tid = threadIdx.x; // 256 threads
  __shared__ float row[512];
  for (int c = tid; c < 512; c += 256) row[c] = h1[(size_t)b * 512 + c];
  __syncthreads();
  const float4* w = (const float4*)(W + (size_t)tid * 512);
  float acc = 0.f;
  for (int c4 = 0; c4 < 128; ++c4) {
    float4 wv = w[c4], rv = ((const float4*)row)[c4];
    acc += wv.x * rv.x + wv.y * rv.y + wv.z * rv.z + wv.w * rv.w;
  }
  acc += bl[tid];
  float gg = bnp[tid], be = bnp[256 + tid], mm = bnp[512 + tid], vv = bnp[768 + tid];
  float y = (acc - mm) * (gg / sqrtf(vv + EPS_BN)) + be;
  h2[(size_t)b * 256 + tid] = (y > 0.f) ? y : 0.2f * y;
}

__global__ void mlp3_kernel(const float* __restrict__ h2, const float* __restrict__ W, // [40][256]
                            const float* __restrict__ bl, float* __restrict__ out) {
  const int b = blockIdx.x, tid = threadIdx.x; // 64 threads
  __shared__ float row[256];
  for (int c = tid; c < 256; c += 64) row[c] = h2[(size_t)b * 256 + c];
  __syncthreads();
  if (tid < 40) {
    float acc = 0.f;
    for (int c = 0; c < 256; ++c) acc += W[tid * 256 + c] * row[c];
    out[(size_t)b * 40 + tid] = acc + bl[tid];
  }
}

// ---------------------------------------------------------------------------
extern "C" void kernel_launch(void* const* d_in, const int* in_sizes, int n_in,
                              void* d_out, int out_size, void* d_ws, size_t ws_size,
                              hipStream_t stream) {
  const float* x   = (const float*)d_in[0];
  // d_in[1] = normal (unused on this path)
  const float* w1  = (const float*)d_in[2];
  const float* w2  = (const float*)d_in[3];
  const float* w3  = (const float*)d_in[4];
  const float* w4  = (const float*)d_in[5];
  const float* w5  = (const float*)d_in[6];
  const float* wl1 = (const float*)d_in[7];
  const float* wl2 = (const float*)d_in[8];
  const float* bl2 = (const float*)d_in[9];
  const float* wl3 = (const float*)d_in[10];
  const float* bl3 = (const float*)d_in[11];
  const float* bn1 = (const float*)d_in[12];
  const float* bn2 = (const float*)d_in[13];
  const float* bn3 = (const float*)d_in[14];
  const float* bn4 = (const float*)d_in[15];
  const float* bn5 = (const float*)d_in[16];
  const float* bn6 = (const float*)d_in[17];
  const float* bn7 = (const float*)d_in[18];
  float* out = (float*)d_out;

  char* ws = (char*)d_ws;
  float* xc   = (float*)(ws);                                   // 32 MiB
  int*   idx  = (int*)  (ws + 33554432);                        // 1.25 MiB
  float* pmax = (float*)(ws + 33554432 + 1310720);              // 4 MiB
  float* psum = (float*)(ws + 33554432 + 1310720 + 4194304);    // 4 MiB
  float* g    = (float*)(ws + 43058176 + 195584);               // [8][2048]
  float* h1   = (float*)(ws + 43319296);                        // [8][512]
  float* h2   = (float*)(ws + 43335680);                        // [8][256]
  float* wt2  = (float*)(ws + 43343872);                        // [128][64]
  float* wt3  = (float*)(ws + 43376640);                        // [128][128]
  float* wt4  = (float*)(ws + 43442176);                        // [256][256]
  float* wt5  = (float*)(ws + 43704320);                        // [512][1024]

  // weight transposes (idempotent, tiny)
  transpose_w<<<(64 * 128 + 255) / 256, 256, 0, stream>>>(w2, wt2, 64, 128);
  transpose_w<<<(128 * 128 + 255) / 256, 256, 0, stream>>>(w3, wt3, 128, 128);
  transpose_w<<<(256 * 256 + 255) / 256, 256, 0, stream>>>(w4, wt4, 256, 256);
  transpose_w<<<(1024 * 512 + 255) / 256, 256, 0, stream>>>(w5, wt5, 1024, 512);

  dim3 gridKNN(NPTS / TQ, 8);

  // EdgeConv 1: x[.,.,3] -> xc[:, :, 0:64]
  knn_kernel<3><<<gridKNN, 256, 0, stream>>>(x, 3, 0, idx);
  edgeconv_tiled<3, 64, 4, 1><<<dim3(NPTS / 4, 8), 256, 0, stream>>>(
      x, 3, 0, idx, w1, bn1, xc, 512, 0);
  // EdgeConv 2: x1 -> xc[:, :, 64:128]   (Wt, ~11KB LDS, 128 thr)
  knn_kernel<64><<<gridKNN, 256, 0, stream>>>(xc, 512, 0, idx);
  edgeconv_wt<64, 64, 2, 1><<<dim3(NPTS / 2, 8), 128, 0, stream>>>(
      xc, 512, 0, idx, wt2, bn2, xc, 512, 64);
  // EdgeConv 3: x2 -> xc[:, :, 128:256]  (Wt, ~11KB LDS, 128 thr)
  knn_kernel<64><<<gridKNN, 256, 0, stream>>>(xc, 512, 64, idx);
  edgeconv_wt<64, 128, 2, 2><<<dim3(NPTS / 2, 8), 128, 0, stream>>>(
      xc, 512, 64, idx, wt3, bn3, xc, 512, 128);
  // EdgeConv 4: x3 -> xc[:, :, 256:512]  (Wt, ~11KB LDS, 128 thr)
  knn_kernel<128><<<gridKNN, 256, 0, stream>>>(xc, 512, 128, idx);
  edgeconv_wt<128, 256, 1, 2><<<dim3(NPTS, 8), 128, 0, stream>>>(
      xc, 512, 128, idx, wt4, bn4, xc, 512, 256);

  // x5 GEMM + bn + act + fused partial max/mean (Wt)
  x5_kernel<<<dim3(128, 8), 256, 0, stream>>>(xc, wt5, bn5, pmax, psum);
  x5_reduce_final<<<dim3(4, 8), 256, 0, stream>>>(pmax, psum, g);

  // Final MLP
  mlp1_kernel<<<8, 512, 0, stream>>>(g, wl1, bn6, h1);
  mlp2_kernel<<<8, 256, 0, stream>>>(h1, wl2, bl2, bn7, h2);
  mlp3_kernel<<<8, 64, 0, stream>>>(h2, wl3, bl3, out);
}